// Round 9
// baseline (171.835 us; speedup 1.0000x reference)
//
#include <hip/hip_runtime.h>

namespace {

constexpr int T_LEN = 512;
constexpr float LOG2E = 1.4426950408889634f;

typedef _Float16 half4 __attribute__((ext_vector_type(4)));
typedef _Float16 half2v __attribute__((ext_vector_type(2)));
typedef float v4f __attribute__((ext_vector_type(4)));

__device__ __forceinline__ float fexp2(float a) {
#if __has_builtin(__builtin_amdgcn_exp2f)
    return __builtin_amdgcn_exp2f(a);
#else
    return exp2f(a);
#endif
}

__device__ __forceinline__ v4f mfma16h(half4 a, half4 b, v4f c) {
#if __has_builtin(__builtin_amdgcn_mfma_f32_16x16x16f16)
    return __builtin_amdgcn_mfma_f32_16x16x16f16(a, b, c, 0, 0, 0);
#else
    v4f d;
    asm volatile("v_mfma_f32_16x16x16_f16 %0, %1, %2, %3\n\ts_nop 7\n\ts_nop 7"
                 : "=v"(d) : "v"(a), "v"(b), "v"(c));
    return d;
#endif
}

__device__ __forceinline__ unsigned pk_f16(float a, float b) {
#if __has_builtin(__builtin_amdgcn_cvt_pkrtz)
    return __builtin_bit_cast(unsigned, __builtin_amdgcn_cvt_pkrtz(a, b));
#else
    half2v r; r[0] = (_Float16)a; r[1] = (_Float16)b;
    return __builtin_bit_cast(unsigned, r);
#endif
}

template<int OFF>
__device__ __forceinline__ unsigned ds_swz_u(unsigned v) {
    return (unsigned)__builtin_amdgcn_ds_swizzle((int)v, OFF);
}

// select d[q] with compile-time vector indices (q = qb1*2 + qb0, per-lane)
__device__ __forceinline__ float sel4(v4f d, bool qb0, bool qb1) {
    float a = qb0 ? d[1] : d[0];
    float b = qb0 ? d[3] : d[2];
    return qb1 ? b : a;
}

struct StreamState {
    half4 hf;      // B-fragment (rows jD..jD+3, f16)
    float hp;      // this lane's h row (fp32 master)
};

__global__ __launch_bounds__(64) void gru_dual(
        const float* __restrict__ x,
        const float* __restrict__ W_ih,
        const float* __restrict__ W_hh,
        const float* __restrict__ b_ih,
        const float* __restrict__ b_hh,
        const float* __restrict__ fc_w,
        const float* __restrict__ fc_b,
        float* __restrict__ out) {
    const int L  = threadIdx.x;      // 0..63
    const int e  = L & 15;           // MFMA column; cols with same (e&3) duplicate
    const int g  = L >> 4;           // row group; D rows jD..jD+3 of col e
    const int jD = g * 4;
    const int q    = (e >> 2) & 3;   // which D-reg (row jD+q) this lane gates
    const bool qb0 = (q & 1) != 0;
    const bool qb1 = (q & 2) != 0;
    const int ecol = e & 3;          // real batch column within a stream
    const int rme  = jD + q;         // the single gate row this lane owns

    const int beA = blockIdx.x * 8 + ecol;       // stream A element
    const int beB = beA + 4;                     // stream B element

    const float sR = -LOG2E;         // sigmoid scaling folded into weights
    const float sN = 2.0f * LOG2E;   // tanh scaling

    // ---- A fragments: W_hh rows (gate out m = e; k = jD..jD+3), scaled,
    //      f16 hi + f16 residual. Shared by both streams.
    half4 ar_hi, ar_lo, az_hi, az_lo, an_hi, an_lo;
#pragma unroll
    for (int i = 0; i < 4; ++i) {
        float wr = W_hh[(0  + e) * 16 + jD + i] * sR;
        float wz = W_hh[(16 + e) * 16 + jD + i] * sR;
        float wn = W_hh[(32 + e) * 16 + jD + i] * sN;
        _Float16 rh = (_Float16)wr; ar_hi[i] = rh; ar_lo[i] = (_Float16)(wr - (float)rh);
        _Float16 zh = (_Float16)wz; az_hi[i] = zh; az_lo[i] = (_Float16)(wz - (float)zh);
        _Float16 nh = (_Float16)wn; an_hi[i] = nh; an_lo[i] = (_Float16)(wn - (float)nh);
    }

    // ---- loop-invariant MFMA C-operands: pure bias vectors (x folded in later)
    v4f c_r, c_z, c_n;
#pragma unroll
    for (int i = 0; i < 4; ++i) {
        int rj = jD + i;
        c_r[i] = (b_ih[rj]      + b_hh[rj])      * sR;
        c_z[i] = (b_ih[16 + rj] + b_hh[16 + rj]) * sR;
        c_n[i] = b_hh[32 + rj] * sN;
    }
    // per-lane selected-row scalars
    const float wihr_s = W_ih[rme]      * sR;
    const float wihz_s = W_ih[16 + rme] * sR;
    const float wihn_s = W_ih[32 + rme] * sN;
    const float bihn_s = b_ih[32 + rme] * sN;

    // ---- x timelines (duplicate lanes of a stream hit identical addresses)
    const float4* xbA = (const float4*)(x + (size_t)beA * T_LEN);
    const float4* xbB = (const float4*)(x + (size_t)beB * T_LEN);
    float4 xcA = xbA[0];
    float4 xcB = xbB[0];

    StreamState SA, SB;
    uint2 hz; hz.x = 0u; hz.y = 0u;
    SA.hf = __builtin_bit_cast(half4, hz); SA.hp = 0.f;
    SB.hf = __builtin_bit_cast(half4, hz); SB.hp = 0.f;

#pragma unroll 1
    for (int c = 0; c < T_LEN / 4; ++c) {        // 4 steps per chunk
        float4 xnA, xnB;
        if (c + 1 < T_LEN / 4) { xnA = xbA[c + 1]; xnB = xbB[c + 1]; }
#pragma unroll
        for (int s = 0; s < 4; ++s) {
            float xtA = (s == 0) ? xcA.x : (s == 1) ? xcA.y : (s == 2) ? xcA.z : xcA.w;
            float xtB = (s == 0) ? xcB.x : (s == 1) ? xcB.y : (s == 2) ? xcB.z : xcB.w;

            // --- both streams' MFMAs issued together (independent chains)
            v4f drA = mfma16h(ar_hi, SA.hf, c_r);
            v4f dzA = mfma16h(az_hi, SA.hf, c_z);
            v4f dnA = mfma16h(an_hi, SA.hf, c_n);
            v4f drB = mfma16h(ar_hi, SB.hf, c_r);
            v4f dzB = mfma16h(az_hi, SB.hf, c_z);
            v4f dnB = mfma16h(an_hi, SB.hf, c_n);
            drA = mfma16h(ar_lo, SA.hf, drA);
            dzA = mfma16h(az_lo, SA.hf, dzA);
            dnA = mfma16h(an_lo, SA.hf, dnA);
            drB = mfma16h(ar_lo, SB.hf, drB);
            dzB = mfma16h(az_lo, SB.hf, dzB);
            dnB = mfma16h(an_lo, SB.hf, dnB);

            // --- gates, stream A
            {
                float d_r = __builtin_fmaf(xtA, wihr_s, sel4(drA, qb0, qb1));
                float d_z = __builtin_fmaf(xtA, wihz_s, sel4(dzA, qb0, qb1));
                float d_n = sel4(dnA, qb0, qb1);
                float Er = fexp2(d_r);
                float Ez = fexp2(d_z);
                float pr = 1.0f + Er;
                float pz = 1.0f + Ez;
                float ip = __builtin_amdgcn_rcpf(pr * pz);
                float r  = ip * pz;
                float z  = ip * pr;
                float xn = __builtin_fmaf(xtA, wihn_s, bihn_s);
                float v  = __builtin_fmaf(r, d_n, xn);
                float n  = __builtin_fmaf(-2.0f,
                              __builtin_amdgcn_rcpf(1.0f + fexp2(v)), 1.0f);
                float hn = __builtin_fmaf(z, SA.hp - n, n);
                SA.hp = hn;
                // reassemble B-frag (intra-wave): xor4 pair, pack, xor8 other pair
                unsigned hbits = __builtin_bit_cast(unsigned, hn);
                unsigned p4    = ds_swz_u<0x101F>(hbits);
                float hprt = __builtin_bit_cast(float, p4);
                float plo = qb0 ? hprt : hn;
                float phi = qb0 ? hn   : hprt;
                unsigned pairu = pk_f16(plo, phi);
                unsigned oth   = ds_swz_u<0x201F>(pairu);
                uint2 hv;
                hv.x = qb1 ? oth   : pairu;
                hv.y = qb1 ? pairu : oth;
                SA.hf = __builtin_bit_cast(half4, hv);
            }
            // --- gates, stream B
            {
                float d_r = __builtin_fmaf(xtB, wihr_s, sel4(drB, qb0, qb1));
                float d_z = __builtin_fmaf(xtB, wihz_s, sel4(dzB, qb0, qb1));
                float d_n = sel4(dnB, qb0, qb1);
                float Er = fexp2(d_r);
                float Ez = fexp2(d_z);
                float pr = 1.0f + Er;
                float pz = 1.0f + Ez;
                float ip = __builtin_amdgcn_rcpf(pr * pz);
                float r  = ip * pz;
                float z  = ip * pr;
                float xn = __builtin_fmaf(xtB, wihn_s, bihn_s);
                float v  = __builtin_fmaf(r, d_n, xn);
                float n  = __builtin_fmaf(-2.0f,
                              __builtin_amdgcn_rcpf(1.0f + fexp2(v)), 1.0f);
                float hn = __builtin_fmaf(z, SB.hp - n, n);
                SB.hp = hn;
                unsigned hbits = __builtin_bit_cast(unsigned, hn);
                unsigned p4    = ds_swz_u<0x101F>(hbits);
                float hprt = __builtin_bit_cast(float, p4);
                float plo = qb0 ? hprt : hn;
                float phi = qb0 ? hn   : hprt;
                unsigned pairu = pk_f16(plo, phi);
                unsigned oth   = ds_swz_u<0x201F>(pairu);
                uint2 hv;
                hv.x = qb1 ? oth   : pairu;
                hv.y = qb1 ? pairu : oth;
                SB.hf = __builtin_bit_cast(half4, hv);
            }
        }
        if (c + 1 < T_LEN / 4) { xcA = xnA; xcB = xnB; }
    }

    // ---- FC: lanes {L & 3 == ecol} hold all 16 rows (g x q) exactly once
    float pA = SA.hp * fc_w[rme];
    float pB = SB.hp * fc_w[rme];
    pA += __shfl_xor(pA, 4, 64);  pB += __shfl_xor(pB, 4, 64);
    pA += __shfl_xor(pA, 8, 64);  pB += __shfl_xor(pB, 8, 64);
    pA += __shfl_xor(pA, 16, 64); pB += __shfl_xor(pB, 16, 64);
    pA += __shfl_xor(pA, 32, 64); pB += __shfl_xor(pB, 32, 64);
    if (L < 4) {
        out[blockIdx.x * 8 + L]     = pA + fc_b[0];
        out[blockIdx.x * 8 + 4 + L] = pB + fc_b[0];
    }
}

} // namespace

extern "C" void kernel_launch(void* const* d_in, const int* in_sizes, int n_in,
                              void* d_out, int out_size, void* d_ws, size_t ws_size,
                              hipStream_t stream) {
    const float* x    = (const float*)d_in[0];
    const float* W_ih = (const float*)d_in[1];
    const float* W_hh = (const float*)d_in[2];
    const float* b_ih = (const float*)d_in[3];
    const float* b_hh = (const float*)d_in[4];
    const float* fc_w = (const float*)d_in[5];
    const float* fc_b = (const float*)d_in[6];
    float* out = (float*)d_out;

    const int B = out_size;               // 8192
    const int blocks = B / 8;             // 2 streams x 4 elements per 1-wave block
    gru_dual<<<blocks, 64, 0, stream>>>(x, W_ih, W_hh, b_ih, b_hh,
                                        fc_w, fc_b, out);
}

// Round 10
// 98.100 us; speedup vs baseline: 1.7516x; 1.7516x over previous
//
#include <hip/hip_runtime.h>

namespace {

constexpr int T_LEN = 512;
constexpr float LOG2E = 1.4426950408889634f;

typedef _Float16 half4 __attribute__((ext_vector_type(4)));
typedef _Float16 half2v __attribute__((ext_vector_type(2)));
typedef float v4f __attribute__((ext_vector_type(4)));

__device__ __forceinline__ float fexp2(float a) {
#if __has_builtin(__builtin_amdgcn_exp2f)
    return __builtin_amdgcn_exp2f(a);
#else
    return exp2f(a);
#endif
}

__device__ __forceinline__ v4f mfma16h(half4 a, half4 b, v4f c) {
#if __has_builtin(__builtin_amdgcn_mfma_f32_16x16x16f16)
    return __builtin_amdgcn_mfma_f32_16x16x16f16(a, b, c, 0, 0, 0);
#else
    v4f d;
    asm volatile("v_mfma_f32_16x16x16_f16 %0, %1, %2, %3\n\ts_nop 7\n\ts_nop 7"
                 : "=v"(d) : "v"(a), "v"(b), "v"(c));
    return d;
#endif
}

__device__ __forceinline__ unsigned pk_f16(float a, float b) {
#if __has_builtin(__builtin_amdgcn_cvt_pkrtz)
    return __builtin_bit_cast(unsigned, __builtin_amdgcn_cvt_pkrtz(a, b));
#else
    half2v r; r[0] = (_Float16)a; r[1] = (_Float16)b;
    return __builtin_bit_cast(unsigned, r);
#endif
}

template<int OFF>
__device__ __forceinline__ unsigned ds_swz_u(unsigned v) {
    return (unsigned)__builtin_amdgcn_ds_swizzle((int)v, OFF);
}

// one (row, element) gate evaluation + h update (identical math to R5/R7)
__device__ __forceinline__ float gru_pair(float drp, float dzp, float dnp,
                                          float xt, float wihn, float bihn,
                                          float hp) {
    float Er = fexp2(drp);
    float Ez = fexp2(dzp);
    float pr = 1.0f + Er;
    float pz = 1.0f + Ez;
    float ip = __builtin_amdgcn_rcpf(pr * pz);
    float r  = ip * pz;                  // sigmoid(r-pre)
    float z  = ip * pr;                  // sigmoid(z-pre)
    float xn = __builtin_fmaf(xt, wihn, bihn);
    float v  = __builtin_fmaf(r, dnp, xn);
    float n  = __builtin_fmaf(-2.0f, __builtin_amdgcn_rcpf(1.0f + fexp2(v)), 1.0f);
    return __builtin_fmaf(z, hp - n, n); // (1-z)*n + z*h
}

__global__ __launch_bounds__(64) void gru_mfma8s(
        const float* __restrict__ x,
        const float* __restrict__ W_ih,
        const float* __restrict__ W_hh,
        const float* __restrict__ b_ih,
        const float* __restrict__ b_hh,
        const float* __restrict__ fc_w,
        const float* __restrict__ fc_b,
        float* __restrict__ out) {
    const int L  = threadIdx.x;      // 0..63
    const int e  = L & 15;           // MFMA column (cols e and e+8 duplicate)
    const int g  = L >> 4;           // row group; D rows jD..jD+3 of col e
    const int jD = g * 4;
    const int ehi  = (e >> 3) & 1;   // 0: gate rows jD,jD+1 ; 1: jD+2,jD+3
    const int ecol = e & 7;          // real batch column within the group
    const int be   = blockIdx.x * 8 + ecol;
    const int r0   = jD + 2 * ehi;   // first of the 2 gate rows this lane owns

    const float sR = -LOG2E;         // sigmoid scaling folded into weights
    const float sN = 2.0f * LOG2E;   // tanh scaling

    // ---- A fragments: W_hh rows (gate out m = e; k = jD..jD+3), scaled,
    //      single f16 (RTN).  3 fragments, 3 MFMAs per step.
    half4 ar_h, az_h, an_h;
#pragma unroll
    for (int i = 0; i < 4; ++i) {
        ar_h[i] = (_Float16)(W_hh[(0  + e) * 16 + jD + i] * sR);
        az_h[i] = (_Float16)(W_hh[(16 + e) * 16 + jD + i] * sR);
        an_h[i] = (_Float16)(W_hh[(32 + e) * 16 + jD + i] * sN);
    }

    // ---- loop-invariant MFMA C-operands: pure bias vectors (xt folded post-sel)
    v4f c_r, c_z, c_n;
#pragma unroll
    for (int i = 0; i < 4; ++i) {
        int rj = jD + i;
        c_r[i] = (b_ih[rj]      + b_hh[rj])      * sR;
        c_z[i] = (b_ih[16 + rj] + b_hh[16 + rj]) * sR;
        c_n[i] = b_hh[32 + rj] * sN;
    }
    // per-lane scalars for this lane's 2 gate rows
    const float wihr0 = W_ih[r0]          * sR, wihr1 = W_ih[r0 + 1]      * sR;
    const float wihz0 = W_ih[16 + r0]     * sR, wihz1 = W_ih[16 + r0 + 1] * sR;
    const float wihn0 = W_ih[32 + r0]     * sN, wihn1 = W_ih[32 + r0 + 1] * sN;
    const float bihn0 = b_ih[32 + r0]     * sN, bihn1 = b_ih[32 + r0 + 1] * sN;

    // ---- x timeline for this column (duplicate lanes hit identical addresses)
    const float4* xb = (const float4*)(x + (size_t)be * T_LEN);
    float4 xc0 = xb[0], xc1 = xb[1], xc2 = xb[2], xc3 = xb[3];

    float hp0 = 0.f, hp1 = 0.f;          // this lane's 2 h rows (fp32 master)
    uint2 hz; hz.x = 0u; hz.y = 0u;
    half4 hf = __builtin_bit_cast(half4, hz);   // B-frag: rows jD..jD+3 (f16)

#pragma unroll 1
    for (int c = 0; c < T_LEN / 16; ++c) {
        float4 xn0, xn1, xn2, xn3;
        if (c + 1 < T_LEN / 16) {
            xn0 = xb[(c + 1) * 4 + 0];
            xn1 = xb[(c + 1) * 4 + 1];
            xn2 = xb[(c + 1) * 4 + 2];
            xn3 = xb[(c + 1) * 4 + 3];
        }
#pragma unroll
        for (int s = 0; s < 16; ++s) {
            float4 q4 = (s < 4) ? xc0 : (s < 8) ? xc1 : (s < 12) ? xc2 : xc3;
            float xt  = ((s & 3) == 0) ? q4.x : ((s & 3) == 1) ? q4.y
                      : ((s & 3) == 2) ? q4.z : q4.w;

            // matvec on MFMA pipe: ONE f16 MFMA per gate, bias in C
            v4f dr = mfma16h(ar_h, hf, c_r);
            v4f dz = mfma16h(az_h, hf, c_z);
            v4f dn = mfma16h(an_h, hf, c_n);

            // column-duplication split: e<8 -> regs [0,1]; e>=8 -> [2,3];
            // fold x-projection in post-selection (1 FMA per gate-row)
            float d_r0 = __builtin_fmaf(xt, wihr0, ehi ? dr[2] : dr[0]);
            float d_r1 = __builtin_fmaf(xt, wihr1, ehi ? dr[3] : dr[1]);
            float d_z0 = __builtin_fmaf(xt, wihz0, ehi ? dz[2] : dz[0]);
            float d_z1 = __builtin_fmaf(xt, wihz1, ehi ? dz[3] : dz[1]);
            float d_n0 = ehi ? dn[2] : dn[0];
            float d_n1 = ehi ? dn[3] : dn[1];

            float h0n = gru_pair(d_r0, d_z0, d_n0, xt, wihn0, bihn0, hp0);
            float h1n = gru_pair(d_r1, d_z1, d_n1, xt, wihn1, bihn1, hp1);
            hp0 = h0n; hp1 = h1n;

            // reassemble B-frag: my rowpair + partner's rowpair (xor 8, intra-wave)
            unsigned mine = pk_f16(h0n, h1n);
            unsigned oth  = ds_swz_u<0x201F>(mine);   // BitMode xor-8 swizzle
            uint2 hv;
            hv.x = ehi ? oth  : mine;    // rows jD, jD+1
            hv.y = ehi ? mine : oth;     // rows jD+2, jD+3
            hf = __builtin_bit_cast(half4, hv);
        }
        if (c + 1 < T_LEN / 16) { xc0 = xn0; xc1 = xn1; xc2 = xn2; xc3 = xn3; }
    }

    // ---- FC: coset {L^8, L^16, L^32} covers all 16 rows of col ecol once
    float p = hp0 * fc_w[r0] + hp1 * fc_w[r0 + 1];
    p += __shfl_xor(p, 8, 64);
    p += __shfl_xor(p, 16, 64);
    p += __shfl_xor(p, 32, 64);
    if (L < 8) out[blockIdx.x * 8 + L] = p + fc_b[0];
}

} // namespace

extern "C" void kernel_launch(void* const* d_in, const int* in_sizes, int n_in,
                              void* d_out, int out_size, void* d_ws, size_t ws_size,
                              hipStream_t stream) {
    const float* x    = (const float*)d_in[0];
    const float* W_ih = (const float*)d_in[1];
    const float* W_hh = (const float*)d_in[2];
    const float* b_ih = (const float*)d_in[3];
    const float* b_hh = (const float*)d_in[4];
    const float* fc_w = (const float*)d_in[5];
    const float* fc_b = (const float*)d_in[6];
    float* out = (float*)d_out;

    const int B = out_size;               // 8192
    const int blocks = B / 8;             // 8 elements per 1-wave block (2x col dup)
    gru_mfma8s<<<blocks, 64, 0, stream>>>(x, W_ih, W_hh, b_ih, b_hh,
                                          fc_w, fc_b, out);
}

// Round 11
// 87.795 us; speedup vs baseline: 1.9572x; 1.1174x over previous
//
#include <hip/hip_runtime.h>

namespace {

constexpr int T_LEN = 512;
constexpr float LOG2E = 1.4426950408889634f;

typedef _Float16 half4 __attribute__((ext_vector_type(4)));
typedef _Float16 half2v __attribute__((ext_vector_type(2)));
typedef float v4f __attribute__((ext_vector_type(4)));

__device__ __forceinline__ float fexp2(float a) {
#if __has_builtin(__builtin_amdgcn_exp2f)
    return __builtin_amdgcn_exp2f(a);
#else
    return exp2f(a);
#endif
}

__device__ __forceinline__ v4f mfma16h(half4 a, half4 b, v4f c) {
#if __has_builtin(__builtin_amdgcn_mfma_f32_16x16x16f16)
    return __builtin_amdgcn_mfma_f32_16x16x16f16(a, b, c, 0, 0, 0);
#else
    v4f d;
    asm volatile("v_mfma_f32_16x16x16_f16 %0, %1, %2, %3\n\ts_nop 7\n\ts_nop 7"
                 : "=v"(d) : "v"(a), "v"(b), "v"(c));
    return d;
#endif
}

__device__ __forceinline__ unsigned pk_f16(float a, float b) {
#if __has_builtin(__builtin_amdgcn_cvt_pkrtz)
    return __builtin_bit_cast(unsigned, __builtin_amdgcn_cvt_pkrtz(a, b));
#else
    half2v r; r[0] = (_Float16)a; r[1] = (_Float16)b;
    return __builtin_bit_cast(unsigned, r);
#endif
}

// DPP mov, compile-time ctrl. row_ror:8 (0x128) == lane XOR 8 within 16-lane rows
// (rotation by 8 in a 16-group is its own inverse, so direction is irrelevant).
template<int CTRL>
__device__ __forceinline__ unsigned dpp_mov_u(unsigned v) {
    return (unsigned)__builtin_amdgcn_mov_dpp((int)v, CTRL, 0xF, 0xF, false);
}

// one (row, element) gate evaluation + h update (identical math to R5/R7/R10)
__device__ __forceinline__ float gru_pair(float drp, float dzp, float dnp,
                                          float xt, float wihn, float bihn,
                                          float hp) {
    float Er = fexp2(drp);
    float Ez = fexp2(dzp);
    float pr = 1.0f + Er;
    float pz = 1.0f + Ez;
    float ip = __builtin_amdgcn_rcpf(pr * pz);
    float r  = ip * pz;                  // sigmoid(r-pre)
    float z  = ip * pr;                  // sigmoid(z-pre)
    float xn = __builtin_fmaf(xt, wihn, bihn);
    float v  = __builtin_fmaf(r, dnp, xn);
    float n  = __builtin_fmaf(-2.0f, __builtin_amdgcn_rcpf(1.0f + fexp2(v)), 1.0f);
    return __builtin_fmaf(z, hp - n, n); // (1-z)*n + z*h
}

__global__ __launch_bounds__(64) void gru_mfma8d(
        const float* __restrict__ x,
        const float* __restrict__ W_ih,
        const float* __restrict__ W_hh,
        const float* __restrict__ b_ih,
        const float* __restrict__ b_hh,
        const float* __restrict__ fc_w,
        const float* __restrict__ fc_b,
        float* __restrict__ out) {
    const int L  = threadIdx.x;      // 0..63
    const int e  = L & 15;           // MFMA column (cols e and e+8 duplicate)
    const int g  = L >> 4;           // row group; D rows jD..jD+3 of col e
    const int jD = g * 4;
    const int ehi  = (e >> 3) & 1;   // 0: gate rows jD,jD+1 ; 1: jD+2,jD+3
    const int ecol = e & 7;          // real batch column within the group
    const int be   = blockIdx.x * 8 + ecol;
    const int r0   = jD + 2 * ehi;   // first of the 2 gate rows this lane owns

    const float sR = -LOG2E;         // sigmoid scaling folded into weights
    const float sN = 2.0f * LOG2E;   // tanh scaling

    // ---- A fragments: W_hh rows (gate out m = e; k = jD..jD+3), scaled,
    //      single f16 (RTN).  3 fragments, 3 MFMAs per step.
    half4 ar_h, az_h, an_h;
#pragma unroll
    for (int i = 0; i < 4; ++i) {
        ar_h[i] = (_Float16)(W_hh[(0  + e) * 16 + jD + i] * sR);
        az_h[i] = (_Float16)(W_hh[(16 + e) * 16 + jD + i] * sR);
        an_h[i] = (_Float16)(W_hh[(32 + e) * 16 + jD + i] * sN);
    }

    // ---- loop-invariant MFMA C-operands: pure bias vectors (xt folded post-sel)
    v4f c_r, c_z, c_n;
#pragma unroll
    for (int i = 0; i < 4; ++i) {
        int rj = jD + i;
        c_r[i] = (b_ih[rj]      + b_hh[rj])      * sR;
        c_z[i] = (b_ih[16 + rj] + b_hh[16 + rj]) * sR;
        c_n[i] = b_hh[32 + rj] * sN;
    }
    // per-lane scalars for this lane's 2 gate rows
    const float wihr0 = W_ih[r0]          * sR, wihr1 = W_ih[r0 + 1]      * sR;
    const float wihz0 = W_ih[16 + r0]     * sR, wihz1 = W_ih[16 + r0 + 1] * sR;
    const float wihn0 = W_ih[32 + r0]     * sN, wihn1 = W_ih[32 + r0 + 1] * sN;
    const float bihn0 = b_ih[32 + r0]     * sN, bihn1 = b_ih[32 + r0 + 1] * sN;

    // ---- x timeline for this column (duplicate lanes hit identical addresses)
    const float4* xb = (const float4*)(x + (size_t)be * T_LEN);
    float4 xc0 = xb[0], xc1 = xb[1], xc2 = xb[2], xc3 = xb[3];

    float hp0 = 0.f, hp1 = 0.f;          // this lane's 2 h rows (fp32 master)
    uint2 hz; hz.x = 0u; hz.y = 0u;
    half4 hf = __builtin_bit_cast(half4, hz);   // B-frag: rows jD..jD+3 (f16)

#pragma unroll 1
    for (int c = 0; c < T_LEN / 16; ++c) {
        float4 xn0, xn1, xn2, xn3;
        if (c + 1 < T_LEN / 16) {
            xn0 = xb[(c + 1) * 4 + 0];
            xn1 = xb[(c + 1) * 4 + 1];
            xn2 = xb[(c + 1) * 4 + 2];
            xn3 = xb[(c + 1) * 4 + 3];
        }
#pragma unroll
        for (int s = 0; s < 16; ++s) {
            float4 q4 = (s < 4) ? xc0 : (s < 8) ? xc1 : (s < 12) ? xc2 : xc3;
            float xt  = ((s & 3) == 0) ? q4.x : ((s & 3) == 1) ? q4.y
                      : ((s & 3) == 2) ? q4.z : q4.w;

            // matvec on MFMA pipe: ONE f16 MFMA per gate, bias in C
            v4f dr = mfma16h(ar_h, hf, c_r);
            v4f dz = mfma16h(az_h, hf, c_z);
            v4f dn = mfma16h(an_h, hf, c_n);

            // column-duplication split: e<8 -> regs [0,1]; e>=8 -> [2,3];
            // fold x-projection in post-selection (1 FMA per gate-row)
            float d_r0 = __builtin_fmaf(xt, wihr0, ehi ? dr[2] : dr[0]);
            float d_r1 = __builtin_fmaf(xt, wihr1, ehi ? dr[3] : dr[1]);
            float d_z0 = __builtin_fmaf(xt, wihz0, ehi ? dz[2] : dz[0]);
            float d_z1 = __builtin_fmaf(xt, wihz1, ehi ? dz[3] : dz[1]);
            float d_n0 = ehi ? dn[2] : dn[0];
            float d_n1 = ehi ? dn[3] : dn[1];

            float h0n = gru_pair(d_r0, d_z0, d_n0, xt, wihn0, bihn0, hp0);
            float h1n = gru_pair(d_r1, d_z1, d_n1, xt, wihn1, bihn1, hp1);
            hp0 = h0n; hp1 = h1n;

            // reassemble B-frag: partner rowpair via DPP row_ror:8 (VALU, ~4 cyc,
            // replaces the ~110-cyc ds_swizzle on the recurrence critical path)
            unsigned mine = pk_f16(h0n, h1n);
            unsigned oth  = dpp_mov_u<0x128>(mine);   // lane XOR 8 within 16-row
            uint2 hv;
            hv.x = ehi ? oth  : mine;    // rows jD, jD+1
            hv.y = ehi ? mine : oth;     // rows jD+2, jD+3
            hf = __builtin_bit_cast(half4, hv);
        }
        if (c + 1 < T_LEN / 16) { xc0 = xn0; xc1 = xn1; xc2 = xn2; xc3 = xn3; }
    }

    // ---- FC: coset {L^8, L^16, L^32} covers all 16 rows of col ecol once
    float p = hp0 * fc_w[r0] + hp1 * fc_w[r0 + 1];
    p += __shfl_xor(p, 8, 64);
    p += __shfl_xor(p, 16, 64);
    p += __shfl_xor(p, 32, 64);
    if (L < 8) out[blockIdx.x * 8 + L] = p + fc_b[0];
}

} // namespace

extern "C" void kernel_launch(void* const* d_in, const int* in_sizes, int n_in,
                              void* d_out, int out_size, void* d_ws, size_t ws_size,
                              hipStream_t stream) {
    const float* x    = (const float*)d_in[0];
    const float* W_ih = (const float*)d_in[1];
    const float* W_hh = (const float*)d_in[2];
    const float* b_ih = (const float*)d_in[3];
    const float* b_hh = (const float*)d_in[4];
    const float* fc_w = (const float*)d_in[5];
    const float* fc_b = (const float*)d_in[6];
    float* out = (float*)d_out;

    const int B = out_size;               // 8192
    const int blocks = B / 8;             // 8 elements per 1-wave block (2x col dup)
    gru_mfma8d<<<blocks, 64, 0, stream>>>(x, W_ih, W_hh, b_ih, b_hh,
                                          fc_w, fc_b, out);
}